// Round 11
// baseline (2389.102 us; speedup 1.0000x reference)
//
#include <hip/hip_runtime.h>
#include <stdint.h>

#define T_   512
#define H_   256
#define OUTD 128

typedef unsigned long long u64;
typedef __attribute__((ext_vector_type(8))) short s8v;
typedef __attribute__((ext_vector_type(4))) float f4v;
typedef __attribute__((ext_vector_type(4))) unsigned u4v;

__device__ __forceinline__ f4v mfma16x16x32(s8v a, s8v b, f4v c) {
  return __builtin_amdgcn_mfma_f32_16x16x32_bf16(a, b, c, 0, 0, 0);
}

// fp32 -> bf16 hi (truncate) + bf16 lo (RN of remainder)
__device__ __forceinline__ void split_bf16(float f, short &hi, short &lo) {
  unsigned u  = __float_as_uint(f);
  unsigned uh = u & 0xffff0000u;
  hi = (short)(uh >> 16);
  float r = f - __uint_as_float(uh);
  unsigned ur = __float_as_uint(r);
  lo = (short)((ur + 0x7fffu + ((ur >> 16) & 1u)) >> 16);
}

__device__ __forceinline__ unsigned pack_hilo(float f) {
  short hi, lo; split_bf16(f, hi, lo);
  return ((unsigned)(unsigned short)hi << 16) | (unsigned)(unsigned short)lo;
}

// 8 packed dwords (hi16|lo16) -> s8v of 8 hi-bf16 and s8v of 8 lo-bf16
__device__ __forceinline__ void unpk(u4v A, u4v B, s8v &hi, s8v &lo) {
  union U { unsigned u[4]; s8v v; };
  U H, L;
  H.u[0] = __builtin_amdgcn_perm(A.y, A.x, 0x07060302u);
  H.u[1] = __builtin_amdgcn_perm(A.w, A.z, 0x07060302u);
  H.u[2] = __builtin_amdgcn_perm(B.y, B.x, 0x07060302u);
  H.u[3] = __builtin_amdgcn_perm(B.w, B.z, 0x07060302u);
  L.u[0] = __builtin_amdgcn_perm(A.y, A.x, 0x05040100u);
  L.u[1] = __builtin_amdgcn_perm(A.w, A.z, 0x05040100u);
  L.u[2] = __builtin_amdgcn_perm(B.y, B.x, 0x05040100u);
  L.u[3] = __builtin_amdgcn_perm(B.w, B.z, 0x05040100u);
  hi = H.v; lo = L.v;
}

__device__ __forceinline__ float sig_(float x) { return 1.f / (1.f + __expf(-x)); }
__device__ __forceinline__ float th_(float x)  { float e = __expf(2.f * x); return 1.f - 2.f / (e + 1.f); }

struct SMem {
  unsigned xpk[16][268];
  unsigned hpk[16][268];
  float gl[4][16][33];
  float bias[128];
};  // ~43.3 KB (1 block/CU)

// === ROUND 11: round-10 base + PIPELINED h-spin (the one change). ===
// The h-detect was round-serialized: issue 16 loads -> wait full agent RT ->
// check -> sleep -> reissue (3-5 serialized RTs when producers stagger).
// Now the 16 rows split into two 8-row halves with independent validity:
// while one half's tags are checked, the other half's loads are in flight,
// so consecutive poll rounds overlap -> detect ~ visibility + ~1 RT.
// Same register footprint (2x8 u64 = old 16), per-half (not per-entry)
// branching avoids r1's mask-overhead failure. s_sleep dropped in this hot
// spin only (a round is always in flight; polls are L2/L3-absorbed).
//
// Exchange-scope history: r8/r9 proved L2-scope (wg store + sc0 load) exchange
// is unsound even with runtime-XCC_ID-verified same-XCD pairing -> agent scope
// (MALL coherence point) is required; its RT is what this round pipelines.
//
// Partition: 32 units/member, 8 members/group, 16 groups/layer, 256 blocks
// total = 1 block/CU. XCD co-location (r6): group members + cross-layer
// partner groups share an XCD under round-robin dispatch (perf heuristic
// only — agent scope keeps mismatches correct). Weights register-resident
// (unified VGPR+AGPR file).
//
// Exchange protocol: entry = u64 (tag<<32 | bf16hi<<16 | bf16lo), tag = step+1.
// bx0 (layer0 h / layer1 x) depth-4 (slot = s&3); bx1 (layer1 own) depth-2.
// Tag-equality spin on exactly the data each thread consumes (8B single-store
// atomicity => tag/data consistent). Own-group recurrence self-synchronizing
// at depth>=2. L0 publishing step s overwrites x(s-4) => needs rflag >= s-3;
// rflag PREFETCHED at step top, evaluated before publish. L1's x(s)
// prefetched before the h-spin, verified after (RT hidden under h RT).
template <int LAYER>
__device__ __forceinline__ void lstm_body(
    SMem* sm,
    const float* __restrict__ xin,
    const float* __restrict__ Wih, const float* __restrict__ Whh,
    const float* __restrict__ bih, const float* __restrict__ bhh,
    u64* bx_x,        // LAYER==1: consumed exchange (layer0 h, depth 4)
    u64* bx_own,      // produced exchange (L0: bx0 depth 4; L1: bx1 depth 2)
    unsigned* rflag,  // [16 groups][8 members], stride 16 dwords
    float* h1l,       // LAYER==1: last h out [256,256]
    int g, int mem)
{
  constexpr int KX  = (LAYER == 0) ? 128 : 256;
  constexpr int NKX = KX / 32;
  constexpr int OD  = (LAYER == 0) ? 4 : 2;   // own exchange depth
  const int tid = threadIdx.x;
  const int w = tid >> 6, lane = tid & 63, n = lane & 15, q = lane >> 4;
  const int bb = tid >> 4, uu = tid & 15;
  const int B0 = g * 16, U0 = mem * 32;

  // ---- weight slice -> register B-fragments (bf16 hi/lo), once ----
  // wave w = gate w; 2 N-tiles of 16 units each (t=0,1)
  s8v wxh[2][NKX], wxl[2][NKX], whhh[2][8], whhl[2][8];
  #pragma unroll
  for (int t = 0; t < 2; ++t) {
    const int row = w * 256 + U0 + t * 16 + n;
    #pragma unroll
    for (int kf = 0; kf < NKX; ++kf) {
      s8v vh, vl;
      #pragma unroll
      for (int j = 0; j < 8; ++j) { short hi, lo; split_bf16(Wih[row * KX + kf * 32 + q * 8 + j], hi, lo); vh[j] = hi; vl[j] = lo; }
      wxh[t][kf] = vh; wxl[t][kf] = vl;
    }
    #pragma unroll
    for (int kf = 0; kf < 8; ++kf) {
      s8v vh, vl;
      #pragma unroll
      for (int j = 0; j < 8; ++j) { short hi, lo; split_bf16(Whh[row * 256 + kf * 32 + q * 8 + j], hi, lo); vh[j] = hi; vl[j] = lo; }
      whhh[t][kf] = vh; whhl[t][kf] = vl;
    }
  }
  if (tid < 128) {
    int gate = tid >> 5, u = tid & 31;
    int grow = gate * 256 + U0 + u;
    sm->bias[tid] = bih[grow] + bhh[grow];
  }

  u64* own = bx_own + (size_t)g * OD * 4096;
  u64* src = (LAYER == 1) ? (bx_x + (size_t)g * 4 * 4096) : nullptr;
  unsigned* rfg    = rflag + g * 128;       // member m's flag at rfg[m*16]
  unsigned* rfself = rfg + mem * 16;

  float c0 = 0.f, c1 = 0.f;

  for (int s = 0; s < T_; ++s) {
    // ---- layer0: fp32 x prefetch (issued early, overlaps spins) ----
    float xv[8];
    if (LAYER == 0) {
      const float* px = xin + ((size_t)(B0 + bb) * T_ + s) * 128 + uu * 8;
      float4 v0 = *(const float4*)px, v1 = *(const float4*)(px + 4);
      xv[0] = v0.x; xv[1] = v0.y; xv[2] = v0.z; xv[3] = v0.w;
      xv[4] = v1.x; xv[5] = v1.y; xv[6] = v1.z; xv[7] = v1.w;
    }

    // ---- layer0: rflag PREFETCH (evaluated just before publish) ----
    unsigned rfv = 0xffffffffu;
    if (LAYER == 0 && s >= 4 && w == 0 && lane < 8)
      rfv = __hip_atomic_load(&rfg[lane * 16], __ATOMIC_RELAXED, __HIP_MEMORY_SCOPE_AGENT);

    // ---- layer1: x PREFETCH (L0 runs ahead; verify after the h spin) ----
    u64 xp[16];
    if (LAYER == 1) {
      const u64* pbx = src + (size_t)(s & 3) * 4096;
      #pragma unroll
      for (int i = 0; i < 16; ++i)
        xp[i] = __hip_atomic_load(&pbx[i * 256 + tid], __ATOMIC_RELAXED, __HIP_MEMORY_SCOPE_AGENT);
    }

    // ---- spin-consume own group's h_{s-1}: PIPELINED two-half poll ----
    if (s > 0) {
      const u64* pbh = own + (size_t)((s - 1) & (OD - 1)) * 4096;
      const unsigned htag = (unsigned)s;
      u64 h0[8], h1[8];
      #pragma unroll
      for (int i = 0; i < 8; ++i)
        h0[i] = __hip_atomic_load(&pbh[i * 256 + tid], __ATOMIC_RELAXED, __HIP_MEMORY_SCOPE_AGENT);
      #pragma unroll
      for (int i = 0; i < 8; ++i)
        h1[i] = __hip_atomic_load(&pbh[(8 + i) * 256 + tid], __ATOMIC_RELAXED, __HIP_MEMORY_SCOPE_AGENT);
      bool ok0 = false, ok1 = false;
      int it = 0;
      for (;;) {
        if (!ok0) {
          bool t = true;
          #pragma unroll
          for (int i = 0; i < 8; ++i) t &= ((unsigned)(h0[i] >> 32) == htag);
          if (t) {
            ok0 = true;
            #pragma unroll
            for (int i = 0; i < 8; ++i) sm->hpk[i][tid] = (unsigned)h0[i];
          } else {
            #pragma unroll
            for (int i = 0; i < 8; ++i)
              h0[i] = __hip_atomic_load(&pbh[i * 256 + tid], __ATOMIC_RELAXED, __HIP_MEMORY_SCOPE_AGENT);
          }
        }
        if (!ok1) {
          bool t = true;
          #pragma unroll
          for (int i = 0; i < 8; ++i) t &= ((unsigned)(h1[i] >> 32) == htag);
          if (t) {
            ok1 = true;
            #pragma unroll
            for (int i = 0; i < 8; ++i) sm->hpk[8 + i][tid] = (unsigned)h1[i];
          } else {
            #pragma unroll
            for (int i = 0; i < 8; ++i)
              h1[i] = __hip_atomic_load(&pbh[(8 + i) * 256 + tid], __ATOMIC_RELAXED, __HIP_MEMORY_SCOPE_AGENT);
          }
        }
        if (ok0 & ok1) break;
        if (++it >= 50000) {               // no-hang safety (stage last-read)
          if (!ok0) {
            #pragma unroll
            for (int i = 0; i < 8; ++i) sm->hpk[i][tid] = (unsigned)h0[i];
          }
          if (!ok1) {
            #pragma unroll
            for (int i = 0; i < 8; ++i) sm->hpk[8 + i][tid] = (unsigned)h1[i];
          }
          break;
        }
      }
    } else {
      #pragma unroll
      for (int i = 0; i < 16; ++i) sm->hpk[i][tid] = 0u;
    }

    // ---- layer1: verify prefetched x tags; rare-miss fallback spin ----
    if (LAYER == 1) {
      const u64* pbx = src + (size_t)(s & 3) * 4096;
      const unsigned xtag = (unsigned)(s + 1);
      bool ok = true;
      #pragma unroll
      for (int i = 0; i < 16; ++i) ok &= ((unsigned)(xp[i] >> 32) == xtag);
      if (!ok) {
        int it = 0;
        for (;;) {
          ok = true;
          #pragma unroll
          for (int i = 0; i < 16; ++i)
            xp[i] = __hip_atomic_load(&pbx[i * 256 + tid], __ATOMIC_RELAXED, __HIP_MEMORY_SCOPE_AGENT);
          #pragma unroll
          for (int i = 0; i < 16; ++i) ok &= ((unsigned)(xp[i] >> 32) == xtag);
          if (ok) break;
          if (++it >= 50000) break;        // no-hang safety
          __builtin_amdgcn_s_sleep(1);
        }
      }
      #pragma unroll
      for (int i = 0; i < 16; ++i)
        sm->xpk[i][tid] = (unsigned)xp[i];
    }

    // ---- layer0: stage fp32 x as packed bf16 hi|lo ----
    if (LAYER == 0) {
      unsigned dp[8];
      #pragma unroll
      for (int j = 0; j < 8; ++j) dp[j] = pack_hilo(xv[j]);
      u4v w0 = {dp[0], dp[1], dp[2], dp[3]};
      u4v w1 = {dp[4], dp[5], dp[6], dp[7]};
      *(u4v*)&sm->xpk[bb][uu * 8]     = w0;
      *(u4v*)&sm->xpk[bb][uu * 8 + 4] = w1;
    }
    __syncthreads();

    // layer1: publish read-progress (all threads' loads completed at barrier)
    if (LAYER == 1 && tid == 0)
      __hip_atomic_store(rfself, (unsigned)(s + 1), __ATOMIC_RELAXED, __HIP_MEMORY_SCOPE_AGENT);

    // ---- bf16x3 MFMA, 2 N-tiles per wave: hi*hi + lo*hi + hi*lo ----
    f4v a00 = {0.f,0.f,0.f,0.f}, a01 = a00, a02 = a00;
    f4v a10 = a00, a11 = a00, a12 = a00;
    #pragma unroll
    for (int kf = 0; kf < NKX; ++kf) {
      u4v A0 = *(const u4v*)&sm->xpk[n][kf * 32 + q * 8];
      u4v A1 = *(const u4v*)&sm->xpk[n][kf * 32 + q * 8 + 4];
      s8v ah, al; unpk(A0, A1, ah, al);
      a00 = mfma16x16x32(ah, wxh[0][kf], a00);
      a01 = mfma16x16x32(al, wxh[0][kf], a01);
      a02 = mfma16x16x32(ah, wxl[0][kf], a02);
      a10 = mfma16x16x32(ah, wxh[1][kf], a10);
      a11 = mfma16x16x32(al, wxh[1][kf], a11);
      a12 = mfma16x16x32(ah, wxl[1][kf], a12);
    }
    #pragma unroll
    for (int kf = 0; kf < 8; ++kf) {
      u4v A0 = *(const u4v*)&sm->hpk[n][kf * 32 + q * 8];
      u4v A1 = *(const u4v*)&sm->hpk[n][kf * 32 + q * 8 + 4];
      s8v ah, al; unpk(A0, A1, ah, al);
      a00 = mfma16x16x32(ah, whhh[0][kf], a00);
      a01 = mfma16x16x32(al, whhh[0][kf], a01);
      a02 = mfma16x16x32(ah, whhl[0][kf], a02);
      a10 = mfma16x16x32(ah, whhh[1][kf], a10);
      a11 = mfma16x16x32(al, whhh[1][kf], a11);
      a12 = mfma16x16x32(ah, whhl[1][kf], a12);
    }
    f4v D0 = a00 + (a01 + a02);
    f4v D1 = a10 + (a11 + a12);
    #pragma unroll
    for (int r = 0; r < 4; ++r) {
      sm->gl[w][q * 4 + r][n]      = D0[r];
      sm->gl[w][q * 4 + r][16 + n] = D1[r];
    }
    __syncthreads();

    // ---- activations + state (2 units per thread: uu and uu+16) ----
    float h0v, h1v;
    {
      float pi = sm->gl[0][bb][uu] + sm->bias[uu];
      float pf = sm->gl[1][bb][uu] + sm->bias[32 + uu];
      float pg = sm->gl[2][bb][uu] + sm->bias[64 + uu];
      float po = sm->gl[3][bb][uu] + sm->bias[96 + uu];
      float ig = sig_(pi), fg = sig_(pf), gg = th_(pg), og = sig_(po);
      c0 = fg * c0 + ig * gg;
      h0v = og * th_(c0);
    }
    {
      int u = uu + 16;
      float pi = sm->gl[0][bb][u] + sm->bias[u];
      float pf = sm->gl[1][bb][u] + sm->bias[32 + u];
      float pg = sm->gl[2][bb][u] + sm->bias[64 + u];
      float po = sm->gl[3][bb][u] + sm->bias[96 + u];
      float ig = sig_(pi), fg = sig_(pf), gg = th_(pg), og = sig_(po);
      c1 = fg * c1 + ig * gg;
      h1v = og * th_(c1);
    }

    // ---- layer0: evaluate prefetched back-pressure (RT already hidden).
    //      Publishing step s overwrites x(s-4): need rflag >= s-3. ----
    if (LAYER == 0) {
      if (s >= 4 && w == 0) {
        const unsigned tgt = (unsigned)(s - 3);
        bool ok = (lane < 8) ? (rfv >= tgt) : true;
        if (!__all((int)ok)) {
          int it = 0;
          for (;;) {
            unsigned v = (lane < 8)
              ? __hip_atomic_load(&rfg[lane * 16], __ATOMIC_RELAXED, __HIP_MEMORY_SCOPE_AGENT)
              : tgt;
            if (__all((int)(v >= tgt))) break;
            if (++it >= 50000) break;
            __builtin_amdgcn_s_sleep(1);
          }
        }
      }
      __syncthreads();
    }

    // ---- publish h (tagged, fire-and-forget; 2 entries/thread) ----
    const u64 tagw = (u64)(unsigned)(s + 1) << 32;
    u64* slot = own + (size_t)(s & (OD - 1)) * 4096 + bb * 256 + U0 + uu;
    __hip_atomic_store(slot,      tagw | (u64)pack_hilo(h0v), __ATOMIC_RELAXED, __HIP_MEMORY_SCOPE_AGENT);
    __hip_atomic_store(slot + 16, tagw | (u64)pack_hilo(h1v), __ATOMIC_RELAXED, __HIP_MEMORY_SCOPE_AGENT);

    if (LAYER == 1 && s == T_ - 1) {
      h1l[(B0 + bb) * H_ + U0 + uu]      = h0v;
      h1l[(B0 + bb) * H_ + U0 + 16 + uu] = h1v;
    }
  }
}

__global__ __launch_bounds__(256, 1) void lstm_fused(
    const float* __restrict__ x,
    const float* __restrict__ Wih0, const float* __restrict__ Whh0,
    const float* __restrict__ bih0, const float* __restrict__ bhh0,
    const float* __restrict__ Wih1, const float* __restrict__ Whh1,
    const float* __restrict__ bih1, const float* __restrict__ bhh1,
    u64* bx0, u64* bx1, unsigned* rflag, float* h1l)
{
  __shared__ SMem sm;
  // XCD co-location map (round-robin dispatch XCD = bid & 7):
  // XCD x hosts: slots 0-7  = L0 group 2x,   members 0-7
  //              slots 8-15 = L0 group 2x+1, members 0-7
  //              slots 16-23= L1 group 2x,   members 0-7
  //              slots 24-31= L1 group 2x+1, members 0-7
  // Perf heuristic only — with agent-scope exchange, a mismatched pair is
  // slower, never incorrect (G16-safe).
  const int bid   = blockIdx.x;
  const int xcd   = bid & 7;
  const int slot  = bid >> 3;            // 0..31
  const int layer = slot >> 4;           // 0 or 1
  const int g     = 2 * xcd + ((slot >> 3) & 1);
  const int mem   = slot & 7;
  if (layer == 0) {
    lstm_body<0>(&sm, x, Wih0, Whh0, bih0, bhh0, nullptr, bx0, rflag, nullptr,
                 g, mem);
  } else {
    lstm_body<1>(&sm, nullptr, Wih1, Whh1, bih1, bhh1, bx0, bx1, rflag, h1l,
                 g, mem);
  }
}

__global__ void fc_kernel(const float* __restrict__ h1l, const float* __restrict__ Wfc,
                          float* __restrict__ out) {
  __shared__ float hs[H_];
  const int b = blockIdx.x, o = threadIdx.x;
  hs[o]       = h1l[b * H_ + o];
  hs[o + 128] = h1l[b * H_ + o + 128];
  __syncthreads();
  float acc = 0.f;
  #pragma unroll 8
  for (int u = 0; u < H_; u += 4) {
    float4 wv = *(const float4*)&Wfc[o * H_ + u];
    acc += wv.x * hs[u] + wv.y * hs[u + 1] + wv.z * hs[u + 2] + wv.w * hs[u + 3];
  }
  out[b * OUTD + o] = acc;
}

extern "C" void kernel_launch(void* const* d_in, const int* in_sizes, int n_in,
                              void* d_out, int out_size, void* d_ws, size_t ws_size,
                              hipStream_t stream) {
  const float* x    = (const float*)d_in[0];
  const float* Wih0 = (const float*)d_in[1];
  const float* Whh0 = (const float*)d_in[2];
  const float* bih0 = (const float*)d_in[3];
  const float* bhh0 = (const float*)d_in[4];
  const float* Wih1 = (const float*)d_in[5];
  const float* Whh1 = (const float*)d_in[6];
  const float* bih1 = (const float*)d_in[7];
  const float* bhh1 = (const float*)d_in[8];
  const float* Wfc  = (const float*)d_in[9];

  // ws layout: bx0 (2 MiB, depth 4) | bx1 (1 MiB, depth 2) | rflag (16 KiB) |
  //            h1l (256 KiB)
  u64*      bx0   = (u64*)d_ws;                 // 16*4*4096
  u64*      bx1   = bx0 + 262144;               // 16*2*4096
  unsigned* rflag = (unsigned*)(bx1 + 131072);  // 16*8*16 used
  float*    h1l   = (float*)(rflag + 4096);     // 256*256

  // rflag must start at 0 (poison 0xAA.. would spoof the >= back-pressure check;
  // exchange tags use equality so poison can never match them).
  hipMemsetAsync(rflag, 0, 4096 * sizeof(unsigned), stream);

  lstm_fused<<<256, 256, 0, stream>>>(x, Wih0, Whh0, bih0, bhh0,
                                      Wih1, Whh1, bih1, bhh1,
                                      bx0, bx1, rflag, h1l);
  fc_kernel<<<256, 128, 0, stream>>>(h1l, Wfc, (float*)d_out);
}